// Round 7
// baseline (1481.084 us; speedup 1.0000x reference)
//
#include <hip/hip_runtime.h>
#include <stdint.h>

#define DIM 16
#define HID 128
#define TN  64            // nodes per block (MLP)
#define ROWF 132          // LDS row stride in floats (128 + 4 pad)
#define EPSF 1e-5f

// ---- bucketed aggregation constants ----
#define NB    98          // buckets of 1024 nodes: covers 100352 >= 100000
#define SLOT  32          // staged entries per region
#define THRESH 16         // flush threshold
#define CAP   33792       // region capacity (mean 32653 + 6.3 sigma)
#define NREG  (2 * NB)    // 98 in-regions + 98 out-regions

// NaN-free tanh via v_exp + v_rcp (rel err ~1e-5; e+1=inf -> rcp=0 -> t=1)
__device__ __forceinline__ float safe_tanh(float x) {
    float a = fabsf(x);
    float e = __expf(2.0f * a);
    float r = __builtin_amdgcn_rcpf(e + 1.0f);
    return copysignf(1.0f - 2.0f * r, x);
}

// ================= Phase 1: bucketed two-phase aggregation ================
__global__ void init_cursors_kernel(int* __restrict__ gcur)
{
    int r = threadIdx.x;
    if (r < NREG) gcur[r] = r * CAP;
}

__device__ __forceinline__ void flush_phase(
    int thresh, int* __restrict__ cnt, int2 (*__restrict__ stage)[SLOT],
    int* __restrict__ gcur, int2* __restrict__ list)
{
    const int wid = threadIdx.x >> 6, lane = threadIdx.x & 63;
    const int bucket = (wid & 1) * 64 + lane;   // 0..127, valid < NB
    const int dir = wid >> 1;                   // 0=in, 1=out
    const bool valid = bucket < NB;
    const int r = dir * NB + (valid ? bucket : 0);
    int c = valid ? cnt[r] : 0;
    bool f = valid && (c >= thresh);
    int n = f ? (c < SLOT ? c : SLOT) : 0;
    int gpos = 0;
    if (f) { gpos = atomicAdd(&gcur[r], n); cnt[r] = 0; }
    unsigned long long mask = __ballot(f);
    while (mask) {
        int sl = __ffsll(mask) - 1; mask &= mask - 1;
        int rb = __shfl(r, sl);
        int nn = __shfl(n, sl);
        int gp = __shfl(gpos, sl);
        if (lane < nn) list[gp + lane] = stage[rb][lane];
    }
}

__global__ void __launch_bounds__(256) bin_kernel(
    const int2* __restrict__ edges, const float* __restrict__ ew, int E,
    int* __restrict__ gcur, int2* __restrict__ list, int nblk)
{
    __shared__ int2 stage[NREG][SLOT];   // 50 KB
    __shared__ int cnt[NREG];
    for (int i = threadIdx.x; i < NREG; i += 256) cnt[i] = 0;
    __syncthreads();

    const int chunk = (E + nblk - 1) / nblk;
    const int e0 = blockIdx.x * chunk;
    const int e1 = min(e0 + chunk, E);

    for (int base = e0; base < e1; base += 512) {
        #pragma unroll
        for (int u = 0; u < 2; ++u) {
            int e = base + threadIdx.x + u * 256;
            if (e < e1) {
                int2 sd = edges[e];                 // x=src, y=dst
                int wb = __float_as_int(ew[e]);
                // in-entry: agg_in[dst] += nodes[src]*w
                int r0 = sd.y >> 10;
                int2 en0 = make_int2(((sd.y & 1023) << 17) | sd.x, wb);
                int p0 = atomicAdd(&cnt[r0], 1);
                if (p0 < SLOT) stage[r0][p0] = en0;
                else list[atomicAdd(&gcur[r0], 1)] = en0;
                // out-entry: agg_out[src] += nodes[dst]*w
                int r1 = NB + (sd.x >> 10);
                int2 en1 = make_int2(((sd.x & 1023) << 17) | sd.y, wb);
                int p1 = atomicAdd(&cnt[r1], 1);
                if (p1 < SLOT) stage[r1][p1] = en1;
                else list[atomicAdd(&gcur[r1], 1)] = en1;
            }
        }
        __syncthreads();
        flush_phase(THRESH, cnt, stage, gcur, list);
        __syncthreads();
    }
    flush_phase(1, cnt, stage, gcur, list);
}

__global__ void __launch_bounds__(256) accum_kernel(
    const float* __restrict__ nodes, const int2* __restrict__ list,
    const int* __restrict__ gcur, float* __restrict__ agg_in,
    float* __restrict__ agg_out, int N)
{
    __shared__ float acc[1024 * DIM];    // 64 KB
    const int r = blockIdx.x;            // 0..NREG-1
    const int dir = (r >= NB) ? 1 : 0;
    const int bucket = dir ? r - NB : r;
    for (int i = threadIdx.x; i < 1024 * DIM; i += 256) acc[i] = 0.f;
    __syncthreads();

    const int base = r * CAP;
    const int len = gcur[r] - base;
    const int t = threadIdx.x >> 4, c = threadIdx.x & 15;
    for (int i0 = 0; i0 < len; i0 += 64) {
        #pragma unroll
        for (int u = 0; u < 4; ++u) {
            int i = i0 + u * 16 + t;
            if (i < len) {
                int2 en = list[base + i];
                int other = en.x & 0x1FFFF;
                int local = en.x >> 17;
                float v = __int_as_float(en.y) * nodes[other * DIM + c];
                atomicAdd(&acc[local * DIM + c], v);
            }
        }
    }
    __syncthreads();

    float* __restrict__ dst = dir ? agg_out : agg_in;
    const int node0 = bucket << 10;
    for (int i = threadIdx.x; i < 1024 * DIM; i += 256) {
        int node = node0 + (i >> 4);
        if (node < N) dst[node * DIM + (i & 15)] = acc[i];
    }
}

// ---------------- fallback: direct atomic scatter (proven) ---------------
__global__ void __launch_bounds__(256) edge_scatter_kernel(
    const float* __restrict__ nodes, const int* __restrict__ edges,
    const float* __restrict__ ew, float* __restrict__ agg_in,
    float* __restrict__ agg_out, int nEdges)
{
    int gid = blockIdx.x * 256 + threadIdx.x;
    int e = gid >> 4;
    if (e >= nEdges) return;
    int c = gid & 15;
    int src = edges[2 * e];
    int dst = edges[2 * e + 1];
    float w  = ew[e];
    atomicAdd(&agg_in[dst * DIM + c], nodes[src * DIM + c] * w);
    atomicAdd(&agg_out[src * DIM + c], nodes[dst * DIM + c] * w);
}

// ---------------- Phase 2: fused 4-layer MLP (round-5 structure) ----------
template<int K>
__device__ __forceinline__ void dense_ln_tanh(
    const float* __restrict__ W, const float* __restrict__ bias,
    const float* __restrict__ g, const float* __restrict__ be,
    float (&X)[TN][ROWF], int tid)
{
    const int c0 = (tid & 31) * 4;   // 32 col-groups cover 128 cols
    const int n0 = (tid >> 5) * 8;   // 8 rows per thread
    float acc[8][4];
    {
        float4 bv = *(const float4*)(bias + c0);
        #pragma unroll
        for (int i = 0; i < 8; ++i) {
            acc[i][0] = bv.x; acc[i][1] = bv.y; acc[i][2] = bv.z; acc[i][3] = bv.w;
        }
    }

    #pragma unroll 2
    for (int k = 0; k < K; k += 4) {
        float xr[8][4];
        #pragma unroll
        for (int i = 0; i < 8; ++i) {
            float4 t = *(const float4*)&X[n0 + i][k];
            xr[i][0] = t.x; xr[i][1] = t.y; xr[i][2] = t.z; xr[i][3] = t.w;
        }
        float w[4][4];
        #pragma unroll
        for (int kk = 0; kk < 4; ++kk) {
            float4 t = *(const float4*)(W + (k + kk) * HID + c0);
            w[kk][0] = t.x; w[kk][1] = t.y; w[kk][2] = t.z; w[kk][3] = t.w;
        }
        #pragma unroll
        for (int kk = 0; kk < 4; ++kk)
            #pragma unroll
            for (int i = 0; i < 8; ++i)
                #pragma unroll
                for (int j = 0; j < 4; ++j) acc[i][j] += xr[i][kk] * w[kk][j];
    }

    float s[8], q[8];
    #pragma unroll
    for (int i = 0; i < 8; ++i) {
        s[i] = acc[i][0] + acc[i][1] + acc[i][2] + acc[i][3];
        q[i] = acc[i][0]*acc[i][0] + acc[i][1]*acc[i][1]
             + acc[i][2]*acc[i][2] + acc[i][3]*acc[i][3];
    }
    #pragma unroll
    for (int m = 1; m <= 16; m <<= 1) {
        #pragma unroll
        for (int i = 0; i < 8; ++i) {
            s[i] += __shfl_xor(s[i], m);
            q[i] += __shfl_xor(q[i], m);
        }
    }

    float4 gv  = *(const float4*)(g + c0);
    float4 bev = *(const float4*)(be + c0);
    float gr[4]  = {gv.x, gv.y, gv.z, gv.w};
    float ber[4] = {bev.x, bev.y, bev.z, bev.w};

    __syncthreads();
    #pragma unroll
    for (int i = 0; i < 8; ++i) {
        float mean = s[i] * (1.0f / HID);
        float var  = fmaxf(q[i] * (1.0f / HID) - mean * mean, 0.0f);
        float r = rsqrtf(var + EPSF);
        float o[4];
        #pragma unroll
        for (int j = 0; j < 4; ++j)
            o[j] = safe_tanh((acc[i][j] - mean) * r * gr[j] + ber[j]);
        *(float4*)&X[n0 + i][c0] = make_float4(o[0], o[1], o[2], o[3]);
    }
    __syncthreads();
}

__global__ void __launch_bounds__(256, 3) mlp_kernel(
    const float* __restrict__ agg_in, const float* __restrict__ agg_out,
    const float* __restrict__ nodes,
    const float* __restrict__ W1, const float* __restrict__ b1, const float* __restrict__ g1, const float* __restrict__ be1,
    const float* __restrict__ W2, const float* __restrict__ b2, const float* __restrict__ g2, const float* __restrict__ be2,
    const float* __restrict__ W3, const float* __restrict__ b3, const float* __restrict__ g3, const float* __restrict__ be3,
    const float* __restrict__ W4, const float* __restrict__ b4, const float* __restrict__ g4, const float* __restrict__ be4,
    float* __restrict__ out, int nNodes)
{
    __shared__ float X[TN][ROWF];

    const int tid = threadIdx.x;
    const int node0 = blockIdx.x * TN;

    for (int i = tid; i < TN * 12; i += 256) {
        int n = i / 12, c4 = i - n * 12;
        int gn = node0 + n;
        float4 v = make_float4(0.f, 0.f, 0.f, 0.f);
        if (gn < nNodes) {
            if (c4 < 4)      v = *(const float4*)(agg_in  + gn * DIM + c4 * 4);
            else if (c4 < 8) v = *(const float4*)(agg_out + gn * DIM + (c4 - 4) * 4);
            else             v = *(const float4*)(nodes   + gn * DIM + (c4 - 8) * 4);
        }
        *(float4*)&X[n][c4 * 4] = v;
    }
    __syncthreads();

    dense_ln_tanh<48>(W1, b1, g1, be1, X, tid);
    dense_ln_tanh<128>(W2, b2, g2, be2, X, tid);
    dense_ln_tanh<128>(W3, b3, g3, be3, X, tid);

    {
        const int c2 = tid & 15;
        const int nb = tid >> 4;   // rows nb + {0,16,32,48}
        float a[4];
        {
            float bv = b4[c2];
            #pragma unroll
            for (int t = 0; t < 4; ++t) a[t] = bv;
        }
        #pragma unroll 2
        for (int k = 0; k < HID; k += 4) {
            float w[4];
            #pragma unroll
            for (int kk = 0; kk < 4; ++kk) w[kk] = W4[(k + kk) * DIM + c2];
            #pragma unroll
            for (int t = 0; t < 4; ++t) {
                float4 x = *(const float4*)&X[nb + 16 * t][k];
                a[t] += x.x * w[0] + x.y * w[1] + x.z * w[2] + x.w * w[3];
            }
        }
        float s[4], q[4];
        #pragma unroll
        for (int t = 0; t < 4; ++t) { s[t] = a[t]; q[t] = a[t] * a[t]; }
        #pragma unroll
        for (int m = 1; m <= 8; m <<= 1) {
            #pragma unroll
            for (int t = 0; t < 4; ++t) {
                s[t] += __shfl_xor(s[t], m);
                q[t] += __shfl_xor(q[t], m);
            }
        }
        float g4v = g4[c2], be4v = be4[c2];
        #pragma unroll
        for (int t = 0; t < 4; ++t) {
            int node = node0 + nb + 16 * t;
            if (node < nNodes) {
                float mean = s[t] * (1.0f / DIM);
                float var  = fmaxf(q[t] * (1.0f / DIM) - mean * mean, 0.0f);
                float o = safe_tanh((a[t] - mean) * rsqrtf(var + EPSF) * g4v + be4v);
                out[(size_t)node * DIM + c2] = o;
            }
        }
    }
}

extern "C" void kernel_launch(void* const* d_in, const int* in_sizes, int n_in,
                              void* d_out, int out_size, void* d_ws, size_t ws_size,
                              hipStream_t stream)
{
    const float* nodes = (const float*)d_in[0];
    const int*   edges = (const int*)d_in[1];
    const float* ew    = (const float*)d_in[2];
    const float *W1 = (const float*)d_in[3],  *b1 = (const float*)d_in[4],
                *g1 = (const float*)d_in[5],  *be1 = (const float*)d_in[6];
    const float *W2 = (const float*)d_in[7],  *b2 = (const float*)d_in[8],
                *g2 = (const float*)d_in[9],  *be2 = (const float*)d_in[10];
    const float *W3 = (const float*)d_in[11], *b3 = (const float*)d_in[12],
                *g3 = (const float*)d_in[13], *be3 = (const float*)d_in[14];
    const float *W4 = (const float*)d_in[15], *b4 = (const float*)d_in[16],
                *g4 = (const float*)d_in[17], *be4 = (const float*)d_in[18];

    const int N = in_sizes[0] / DIM;     // 100000
    const int E = in_sizes[2];           // 3200000

    // ws layout
    auto align256 = [](size_t x) { return (x + 255) & ~(size_t)255; };
    size_t o = 0;
    size_t agg_in_off  = o; o = align256(o + (size_t)N * DIM * 4);
    size_t agg_out_off = o; o = align256(o + (size_t)N * DIM * 4);
    size_t gcur_off    = o; o = align256(o + (size_t)NREG * 4);
    size_t list_off    = o; o = align256(o + (size_t)NREG * CAP * 8 + 4096);
    size_t need = o;

    float* agg_in  = (float*)((char*)d_ws + agg_in_off);
    float* agg_out = (float*)((char*)d_ws + agg_out_off);

    if (ws_size >= need) {
        int*  gcur = (int*)((char*)d_ws + gcur_off);
        int2* list = (int2*)((char*)d_ws + list_off);

        init_cursors_kernel<<<1, 256, 0, stream>>>(gcur);
        const int nblk = 784;
        bin_kernel<<<nblk, 256, 0, stream>>>((const int2*)edges, ew, E,
                                             gcur, list, nblk);
        accum_kernel<<<NREG, 256, 0, stream>>>(nodes, list, gcur,
                                               agg_in, agg_out, N);
    } else {
        hipMemsetAsync(d_ws, 0, (size_t)2 * N * DIM * 4, stream);
        long long ethreads = (long long)E * 16;
        int egrid = (int)((ethreads + 255) / 256);
        edge_scatter_kernel<<<egrid, 256, 0, stream>>>(nodes, edges, ew,
                                                       agg_in, agg_out, E);
    }

    int mgrid = (N + TN - 1) / TN;
    mlp_kernel<<<mgrid, 256, 0, stream>>>(agg_in, agg_out, nodes,
        W1, b1, g1, be1, W2, b2, g2, be2, W3, b3, g3, be3, W4, b4, g4, be4,
        (float*)d_out, N);
}

// Round 10
// 1090.540 us; speedup vs baseline: 1.3581x; 1.3581x over previous
//
#include <hip/hip_runtime.h>
#include <stdint.h>

#define DIM 16
#define HID 128
#define TN  64            // nodes per block (MLP)
#define ROWF 132          // LDS row stride in floats (128 + 4 pad; mult of 4 for 16B align)
#define EPSF 1e-5f

// ---- bucketed aggregation constants ----
#define NB    98          // buckets of 1024 nodes: covers 100352 >= 100000
#define SLOT  32          // staged entries per region
#define THRESH 16         // flush threshold
#define CAP   33792       // region capacity (mean 32768 + ~5.7 sigma)
#define NREG  (2 * NB)    // 98 in-regions + 98 out-regions

// NaN-free tanh via v_exp + v_rcp (rel err ~1e-5)
__device__ __forceinline__ float safe_tanh(float x) {
    float a = fabsf(x);
    float e = __expf(2.0f * a);
    float r = __builtin_amdgcn_rcpf(e + 1.0f);
    return copysignf(1.0f - 2.0f * r, x);
}

// ================= Phase 1: bucketed two-phase aggregation ================
__global__ void init_cursors_kernel(int* __restrict__ gcur)
{
    int r = threadIdx.x;
    if (r < NREG) gcur[r] = r * CAP;
}

// r7-proven single-region flush: one flushing region per ballot iteration,
// lanes 0..nn-1 copy its staged entries.
__device__ __forceinline__ void flush_phase(
    int thresh, int* __restrict__ cnt, int2 (*__restrict__ stage)[SLOT],
    int* __restrict__ gcur, int2* __restrict__ list)
{
    const int wid = threadIdx.x >> 6, lane = threadIdx.x & 63;
    const int bucket = (wid & 1) * 64 + lane;   // 0..127, valid < NB
    const int dir = wid >> 1;                   // 0=in, 1=out
    const bool valid = bucket < NB;
    const int r = dir * NB + (valid ? bucket : 0);
    int c = valid ? cnt[r] : 0;
    bool f = valid && (c >= thresh);
    int n = f ? (c < SLOT ? c : SLOT) : 0;
    int gpos = 0;
    if (f) { gpos = atomicAdd(&gcur[r], n); cnt[r] = 0; }
    unsigned long long mask = __ballot(f);
    while (mask) {
        int sl = __ffsll(mask) - 1; mask &= mask - 1;
        int rb = __shfl(r, sl);
        int nn = __shfl(n, sl);
        int gp = __shfl(gpos, sl);
        if (lane < nn) list[gp + lane] = stage[rb][lane];
    }
}

__global__ void __launch_bounds__(256) bin_kernel(
    const int2* __restrict__ edges, const float* __restrict__ ew, int E,
    int* __restrict__ gcur, int2* __restrict__ list, int nblk)
{
    __shared__ int2 stage[NREG][SLOT];   // ~50 KB
    __shared__ int cnt[NREG];
    for (int i = threadIdx.x; i < NREG; i += 256) cnt[i] = 0;
    __syncthreads();

    const int chunk = (E + nblk - 1) / nblk;
    const int e0 = blockIdx.x * chunk;
    const int e1 = min(e0 + chunk, E);

    for (int base = e0; base < e1; base += 512) {
        #pragma unroll
        for (int u = 0; u < 2; ++u) {
            int e = base + threadIdx.x + u * 256;
            if (e < e1) {
                int2 sd = edges[e];                 // x=src, y=dst
                int wb = __float_as_int(ew[e]);
                int r0 = sd.y >> 10;                // in: agg_in[dst]+=nodes[src]*w
                int2 en0 = make_int2(((sd.y & 1023) << 17) | sd.x, wb);
                int p0 = atomicAdd(&cnt[r0], 1);
                if (p0 < SLOT) stage[r0][p0] = en0;
                else list[atomicAdd(&gcur[r0], 1)] = en0;
                int r1 = NB + (sd.x >> 10);         // out: agg_out[src]+=nodes[dst]*w
                int2 en1 = make_int2(((sd.x & 1023) << 17) | sd.y, wb);
                int p1 = atomicAdd(&cnt[r1], 1);
                if (p1 < SLOT) stage[r1][p1] = en1;
                else list[atomicAdd(&gcur[r1], 1)] = en1;
            }
        }
        __syncthreads();
        flush_phase(THRESH, cnt, stage, gcur, list);
        __syncthreads();
    }
    flush_phase(1, cnt, stage, gcur, list);
}

// ONLY change vs r7: 1024 threads (16 waves) + 8 entries in flight per
// thread, explicit guards on load and atomic (no padding-entry trick).
__global__ void __launch_bounds__(1024) accum_kernel(
    const float* __restrict__ nodes, const int2* __restrict__ list,
    const int* __restrict__ gcur, float* __restrict__ agg_in,
    float* __restrict__ agg_out, int N)
{
    __shared__ float acc[1024 * DIM];    // 64 KB
    const int r = blockIdx.x;
    const int dir = (r >= NB) ? 1 : 0;
    const int bucket = dir ? r - NB : r;
    for (int i = threadIdx.x; i < 1024 * DIM; i += 1024) acc[i] = 0.f;
    __syncthreads();

    const int base = r * CAP;
    const int len = gcur[r] - base;
    const int t = threadIdx.x >> 4, c = threadIdx.x & 15;   // t 0..63
    for (int i0 = 0; i0 < len; i0 += 512) {
        int2 en[8]; int ok[8];
        #pragma unroll
        for (int u = 0; u < 8; ++u) {
            int i = i0 + u * 64 + t;
            ok[u] = (i < len);
            en[u] = ok[u] ? list[base + i] : make_int2(0, 0);
        }
        float nv[8];
        #pragma unroll
        for (int u = 0; u < 8; ++u)
            nv[u] = nodes[(en[u].x & 0x1FFFF) * DIM + c];
        #pragma unroll
        for (int u = 0; u < 8; ++u)
            if (ok[u]) atomicAdd(&acc[(en[u].x >> 17) * DIM + c],
                                 __int_as_float(en[u].y) * nv[u]);
    }
    __syncthreads();

    float* __restrict__ dst = dir ? agg_out : agg_in;
    const int node0 = bucket << 10;
    for (int i = threadIdx.x; i < 1024 * DIM; i += 1024) {
        int node = node0 + (i >> 4);
        if (node < N) dst[node * DIM + (i & 15)] = acc[i];
    }
}

// ---------------- fallback: direct atomic scatter (proven) ---------------
__global__ void __launch_bounds__(256) edge_scatter_kernel(
    const float* __restrict__ nodes, const int* __restrict__ edges,
    const float* __restrict__ ew, float* __restrict__ agg_in,
    float* __restrict__ agg_out, int nEdges)
{
    int gid = blockIdx.x * 256 + threadIdx.x;
    int e = gid >> 4;
    if (e >= nEdges) return;
    int c = gid & 15;
    int src = edges[2 * e];
    int dst = edges[2 * e + 1];
    float w  = ew[e];
    atomicAdd(&agg_in[dst * DIM + c], nodes[src * DIM + c] * w);
    atomicAdd(&agg_out[src * DIM + c], nodes[dst * DIM + c] * w);
}

// ---------------- Phase 2: fused 4-layer MLP (r5/r7-proven structure) -----
template<int K>
__device__ __forceinline__ void dense_ln_tanh(
    const float* __restrict__ W, const float* __restrict__ bias,
    const float* __restrict__ g, const float* __restrict__ be,
    float (&X)[TN][ROWF], int tid)
{
    const int c0 = (tid & 31) * 4;   // 32 col-groups cover 128 cols
    const int n0 = (tid >> 5) * 8;   // 8 rows per thread
    float acc[8][4];
    {
        float4 bv = *(const float4*)(bias + c0);
        #pragma unroll
        for (int i = 0; i < 8; ++i) {
            acc[i][0] = bv.x; acc[i][1] = bv.y; acc[i][2] = bv.z; acc[i][3] = bv.w;
        }
    }

    #pragma unroll 2
    for (int k = 0; k < K; k += 4) {
        float xr[8][4];
        #pragma unroll
        for (int i = 0; i < 8; ++i) {
            float4 t = *(const float4*)&X[n0 + i][k];
            xr[i][0] = t.x; xr[i][1] = t.y; xr[i][2] = t.z; xr[i][3] = t.w;
        }
        float w[4][4];
        #pragma unroll
        for (int kk = 0; kk < 4; ++kk) {
            float4 t = *(const float4*)(W + (k + kk) * HID + c0);
            w[kk][0] = t.x; w[kk][1] = t.y; w[kk][2] = t.z; w[kk][3] = t.w;
        }
        #pragma unroll
        for (int kk = 0; kk < 4; ++kk)
            #pragma unroll
            for (int i = 0; i < 8; ++i)
                #pragma unroll
                for (int j = 0; j < 4; ++j) acc[i][j] += xr[i][kk] * w[kk][j];
    }

    float s[8], q[8];
    #pragma unroll
    for (int i = 0; i < 8; ++i) {
        s[i] = acc[i][0] + acc[i][1] + acc[i][2] + acc[i][3];
        q[i] = acc[i][0]*acc[i][0] + acc[i][1]*acc[i][1]
             + acc[i][2]*acc[i][2] + acc[i][3]*acc[i][3];
    }
    #pragma unroll
    for (int m = 1; m <= 16; m <<= 1) {
        #pragma unroll
        for (int i = 0; i < 8; ++i) {
            s[i] += __shfl_xor(s[i], m);
            q[i] += __shfl_xor(q[i], m);
        }
    }

    float4 gv  = *(const float4*)(g + c0);
    float4 bev = *(const float4*)(be + c0);
    float gr[4]  = {gv.x, gv.y, gv.z, gv.w};
    float ber[4] = {bev.x, bev.y, bev.z, bev.w};

    __syncthreads();
    #pragma unroll
    for (int i = 0; i < 8; ++i) {
        float mean = s[i] * (1.0f / HID);
        float var  = fmaxf(q[i] * (1.0f / HID) - mean * mean, 0.0f);
        float r = rsqrtf(var + EPSF);
        float o[4];
        #pragma unroll
        for (int j = 0; j < 4; ++j)
            o[j] = safe_tanh((acc[i][j] - mean) * r * gr[j] + ber[j]);
        *(float4*)&X[n0 + i][c0] = make_float4(o[0], o[1], o[2], o[3]);
    }
    __syncthreads();
}

__global__ void __launch_bounds__(256, 3) mlp_kernel(
    const float* __restrict__ agg_in, const float* __restrict__ agg_out,
    const float* __restrict__ nodes,
    const float* __restrict__ W1, const float* __restrict__ b1, const float* __restrict__ g1, const float* __restrict__ be1,
    const float* __restrict__ W2, const float* __restrict__ b2, const float* __restrict__ g2, const float* __restrict__ be2,
    const float* __restrict__ W3, const float* __restrict__ b3, const float* __restrict__ g3, const float* __restrict__ be3,
    const float* __restrict__ W4, const float* __restrict__ b4, const float* __restrict__ g4, const float* __restrict__ be4,
    float* __restrict__ out, int nNodes)
{
    __shared__ float X[TN][ROWF];

    const int tid = threadIdx.x;
    const int node0 = blockIdx.x * TN;

    for (int i = tid; i < TN * 12; i += 256) {
        int n = i / 12, c4 = i - n * 12;
        int gn = node0 + n;
        float4 v = make_float4(0.f, 0.f, 0.f, 0.f);
        if (gn < nNodes) {
            if (c4 < 4)      v = *(const float4*)(agg_in  + gn * DIM + c4 * 4);
            else if (c4 < 8) v = *(const float4*)(agg_out + gn * DIM + (c4 - 4) * 4);
            else             v = *(const float4*)(nodes   + gn * DIM + (c4 - 8) * 4);
        }
        *(float4*)&X[n][c4 * 4] = v;
    }
    __syncthreads();

    dense_ln_tanh<48>(W1, b1, g1, be1, X, tid);
    dense_ln_tanh<128>(W2, b2, g2, be2, X, tid);
    dense_ln_tanh<128>(W3, b3, g3, be3, X, tid);

    {
        const int c2 = tid & 15;
        const int nb = tid >> 4;   // rows nb + {0,16,32,48}
        float a[4];
        {
            float bv = b4[c2];
            #pragma unroll
            for (int t = 0; t < 4; ++t) a[t] = bv;
        }
        #pragma unroll 2
        for (int k = 0; k < HID; k += 4) {
            float w[4];
            #pragma unroll
            for (int kk = 0; kk < 4; ++kk) w[kk] = W4[(k + kk) * DIM + c2];
            #pragma unroll
            for (int t = 0; t < 4; ++t) {
                float4 x = *(const float4*)&X[nb + 16 * t][k];
                a[t] += x.x * w[0] + x.y * w[1] + x.z * w[2] + x.w * w[3];
            }
        }
        float s[4], q[4];
        #pragma unroll
        for (int t = 0; t < 4; ++t) { s[t] = a[t]; q[t] = a[t] * a[t]; }
        #pragma unroll
        for (int m = 1; m <= 8; m <<= 1) {
            #pragma unroll
            for (int t = 0; t < 4; ++t) {
                s[t] += __shfl_xor(s[t], m);
                q[t] += __shfl_xor(q[t], m);
            }
        }
        float g4v = g4[c2], be4v = be4[c2];
        #pragma unroll
        for (int t = 0; t < 4; ++t) {
            int node = node0 + nb + 16 * t;
            if (node < nNodes) {
                float mean = s[t] * (1.0f / DIM);
                float var  = fmaxf(q[t] * (1.0f / DIM) - mean * mean, 0.0f);
                float o = safe_tanh((a[t] - mean) * rsqrtf(var + EPSF) * g4v + be4v);
                out[(size_t)node * DIM + c2] = o;
            }
        }
    }
}

extern "C" void kernel_launch(void* const* d_in, const int* in_sizes, int n_in,
                              void* d_out, int out_size, void* d_ws, size_t ws_size,
                              hipStream_t stream)
{
    const float* nodes = (const float*)d_in[0];
    const int*   edges = (const int*)d_in[1];
    const float* ew    = (const float*)d_in[2];
    const float *W1 = (const float*)d_in[3],  *b1 = (const float*)d_in[4],
                *g1 = (const float*)d_in[5],  *be1 = (const float*)d_in[6];
    const float *W2 = (const float*)d_in[7],  *b2 = (const float*)d_in[8],
                *g2 = (const float*)d_in[9],  *be2 = (const float*)d_in[10];
    const float *W3 = (const float*)d_in[11], *b3 = (const float*)d_in[12],
                *g3 = (const float*)d_in[13], *be3 = (const float*)d_in[14];
    const float *W4 = (const float*)d_in[15], *b4 = (const float*)d_in[16],
                *g4 = (const float*)d_in[17], *be4 = (const float*)d_in[18];

    const int N = in_sizes[0] / DIM;     // 100000
    const int E = in_sizes[2];           // 3200000

    auto align256 = [](size_t x) { return (x + 255) & ~(size_t)255; };
    size_t o = 0;
    size_t agg_in_off  = o; o = align256(o + (size_t)N * DIM * 4);
    size_t agg_out_off = o; o = align256(o + (size_t)N * DIM * 4);
    size_t gcur_off    = o; o = align256(o + (size_t)NREG * 4);
    size_t list_off    = o; o = align256(o + (size_t)NREG * CAP * 8 + 4096);
    size_t need = o;

    float* agg_in  = (float*)((char*)d_ws + agg_in_off);
    float* agg_out = (float*)((char*)d_ws + agg_out_off);

    if (ws_size >= need) {
        int*  gcur = (int*)((char*)d_ws + gcur_off);
        int2* list = (int2*)((char*)d_ws + list_off);

        init_cursors_kernel<<<1, 256, 0, stream>>>(gcur);
        const int nblk = 784;
        bin_kernel<<<nblk, 256, 0, stream>>>((const int2*)edges, ew, E,
                                             gcur, list, nblk);
        accum_kernel<<<NREG, 1024, 0, stream>>>(nodes, list, gcur,
                                                agg_in, agg_out, N);
    } else {
        hipMemsetAsync(d_ws, 0, (size_t)2 * N * DIM * 4, stream);
        long long ethreads = (long long)E * 16;
        int egrid = (int)((ethreads + 255) / 256);
        edge_scatter_kernel<<<egrid, 256, 0, stream>>>(nodes, edges, ew,
                                                       agg_in, agg_out, E);
    }

    int mgrid = (N + TN - 1) / TN;
    mlp_kernel<<<mgrid, 256, 0, stream>>>(agg_in, agg_out, nodes,
        W1, b1, g1, be1, W2, b2, g2, be2, W3, b3, g3, be3, W4, b4, g4, be4,
        (float*)d_out, N);
}